// Round 9
// baseline (314.593 us; speedup 1.0000x reference)
//
#include <hip/hip_runtime.h>
#include <hip/hip_bf16.h>

// B=16, T=512, E=256, A=8. Inputs f32 (+int32 mask), outputs f32:
//   d_out: [ output 16*512*256 | attn 128*512*512 ]  (both f32)
// Pipeline: prep(sentbf, sentFB, Wp) -> k_attn(Gram+softmax, f32 attn out)
//   -> k_pv (attn @ atr*sent -> X bf16 row-major, flat-reshape baked in)
//   -> k_out (X @ W^T + bias).
// R9 fix: k_attn S-buffer stride bug (R8 wrote past row stride 532; max
// offset was 571 -> row/LDS corruption). Now plain padded S[16][516] with
// contiguous-quad column ownership (c = i4*64 + cl*4 + q).

#define Bt 16
#define Tt 512
#define Et 256
#define At 8

typedef __attribute__((ext_vector_type(8))) short short8;   // 8 x bf16
typedef __attribute__((ext_vector_type(4))) float floatx4;

static __device__ __forceinline__ unsigned short f2bf(float x) {
    union { float f; unsigned u; } v; v.f = x;
    unsigned r = v.u + 0x7fffu + ((v.u >> 16) & 1u);  // RNE
    return (unsigned short)(r >> 16);
}

static __device__ __forceinline__ floatx4 mfma16(short8 a, short8 b, floatx4 c) {
    return __builtin_amdgcn_mfma_f32_16x16x32_bf16(a, b, c, 0, 0, 0);
}

// pack 8 consecutive f32 -> 8 bf16 (round-half-away via +0x8000, v_perm)
static __device__ __forceinline__ short8 pack8(const float* __restrict__ p) {
    uint4 lo = *(const uint4*)p;
    uint4 hi = *(const uint4*)(p + 4);
    union { short8 s; unsigned u[4]; } r;
    r.u[0] = __builtin_amdgcn_perm(lo.y + 0x8000u, lo.x + 0x8000u, 0x07060302u);
    r.u[1] = __builtin_amdgcn_perm(lo.w + 0x8000u, lo.z + 0x8000u, 0x07060302u);
    r.u[2] = __builtin_amdgcn_perm(hi.y + 0x8000u, hi.x + 0x8000u, 0x07060302u);
    r.u[3] = __builtin_amdgcn_perm(hi.w + 0x8000u, hi.z + 0x8000u, 0x07060302u);
    return r.s;
}

// ---- prep: sentbf row-major + sentFB (B-frag-major sent^T) ----------------
// sentFB block (bb, et, sc): 512 shorts lane-major; elem(l16,quad,j) =
//   sent[bb][sc*32+quad*8+j][et*16+l16]
__global__ __launch_bounds__(256) void k_prep_sent(const float* __restrict__ sent,
                                                   unsigned short* __restrict__ sentbf,
                                                   unsigned short* __restrict__ sentFB) {
    int bb = blockIdx.z;
    int s0 = blockIdx.x * 32;       // 16
    int e0 = blockIdx.y * 32;       // 8
    __shared__ float tile[32][33];
    int c  = threadIdx.x & 31;
    int r4 = threadIdx.x >> 5;
    for (int i = 0; i < 4; ++i) {
        int r = r4 + 8 * i;
        int gi = (bb * Tt + s0 + r) * Et + e0 + c;
        float v = sent[gi];
        sentbf[gi] = f2bf(v);
        tile[r][c] = v;
    }
    __syncthreads();
    int wave = threadIdx.x >> 6, lane = threadIdx.x & 63, quad = lane >> 4, l16 = lane & 15;
    if (wave < 2) {
        int h = wave;                       // e-tile half
        int et = (e0 >> 4) + h;
        float tmp[8];
#pragma unroll
        for (int j = 0; j < 8; ++j) tmp[j] = tile[quad * 8 + j][h * 16 + l16];
        union { short8 s; unsigned short e[8]; } u;
#pragma unroll
        for (int j = 0; j < 8; ++j) u.e[j] = f2bf(tmp[j]);
        *(short8*)(sentFB + (((size_t)(bb * 16 + et) * 16 + (s0 >> 5)) << 9) + lane * 8) = u.s;
    }
}

// ---- prep: Wp (B-frag-major W) -------------------------------------------
// Wp block (nt, kc): elem(l16,quad,j) = W[nt*16+l16][kc*32+quad*8+j]
__global__ __launch_bounds__(256) void k_prep_w(const float* __restrict__ W,
                                                unsigned short* __restrict__ Wp) {
    int nt = blockIdx.x;                  // 16
    int wave = threadIdx.x >> 6, lane = threadIdx.x & 63, quad = lane >> 4, l16 = lane & 15;
    const int KK = At * Et;               // 2048
    for (int p = 0; p < 16; ++p) {
        int kc = wave + 4 * p;            // 64
        const float* src = W + (size_t)(nt * 16 + l16) * KK + kc * 32 + quad * 8;
        union { short8 s; unsigned short e[8]; } u;
#pragma unroll
        for (int j = 0; j < 8; ++j) u.e[j] = f2bf(src[j]);
        *(short8*)(Wp + (((size_t)nt * 64 + kc) << 9) + lane * 8) = u.s;
    }
}

// ---- K1: Gram via MFMA, mask folded at S-write, coalesced f32 stores -----
__global__ __launch_bounds__(256) void k_attn(const unsigned short* __restrict__ sent,
                                              const int* __restrict__ mask,
                                              const float* __restrict__ atr,
                                              float* __restrict__ attnf) {
    int bb = blockIdx.y;
    int t0 = blockIdx.x * 16;
    __shared__ float S[16][516];      // plain padded; stride 516 (= 4 mod 32)
    __shared__ float msk[512];
    __shared__ float mrowv[16];
    int tid = threadIdx.x;
    for (int i = tid; i < 512; i += 256) msk[i] = (mask[bb * Tt + i] != 0) ? 1.0f : 0.0f;
    if (tid < 16) mrowv[tid] = (mask[bb * Tt + t0 + tid] != 0) ? 1.0f : 0.0f;
    __syncthreads();

    int wave = tid >> 6, lane = tid & 63, quad = lane >> 4, l16 = lane & 15;

    const unsigned short* Abase = sent + (bb * Tt + t0 + l16) * Et + quad * 8;
    short8 af[8];
#pragma unroll
    for (int kk = 0; kk < 8; ++kk) af[kk] = *(const short8*)(Abase + kk * 32);

#pragma unroll
    for (int i = 0; i < 8; ++i) {
        int nt = wave * 8 + i;
        const unsigned short* Bbase = sent + (bb * Tt + nt * 16 + l16) * Et + quad * 8;
        floatx4 c = {0.f, 0.f, 0.f, 0.f};
#pragma unroll
        for (int kk = 0; kk < 8; ++kk) {
            short8 bf = *(const short8*)(Bbase + kk * 32);
            c = mfma16(af[kk], bf, c);
        }
#pragma unroll
        for (int r = 0; r < 4; ++r) {
            int cidx = nt * 16 + l16;
            S[quad * 4 + r][cidx] = c[r] * msk[cidx] * mrowv[quad * 4 + r];
        }
    }
    __syncthreads();

    // softmax: thread (row=tid>>4, cl=tid&15) owns cols c = i4*64 + cl*4 + q
    int row = tid >> 4, cl = tid & 15;
    float w[32];
    float wmax = -1e30f;
#pragma unroll
    for (int i4 = 0; i4 < 8; ++i4) {
        float4 v = *(const float4*)&S[row][i4 * 64 + cl * 4];
        w[i4 * 4 + 0] = v.x; w[i4 * 4 + 1] = v.y; w[i4 * 4 + 2] = v.z; w[i4 * 4 + 3] = v.w;
        wmax = fmaxf(wmax, fmaxf(fmaxf(v.x, v.y), fmaxf(v.z, v.w)));
    }
#pragma unroll
    for (int off = 8; off >= 1; off >>= 1) wmax = fmaxf(wmax, __shfl_xor(wmax, off, 64));

    for (int a = 0; a < At; ++a) {
        float av = atr[bb * At + a];
        float coef = av * av * (1.0f / 16.0f);
        float mx = coef * wmax;
        float p[32];
        float sum = 0.f;
#pragma unroll
        for (int j = 0; j < 32; ++j) {
            float e = __expf(fmaf(coef, w[j], -mx));
            p[j] = e;
            sum += e;
        }
#pragma unroll
        for (int off = 8; off >= 1; off >>= 1) sum += __shfl_xor(sum, off, 64);
        float inv = 1.0f / sum;
        float* orow = attnf + ((size_t)(bb * At + a) * Tt + (t0 + row)) * Tt;
#pragma unroll
        for (int i4 = 0; i4 < 8; ++i4) {
            float4 v;
            v.x = p[i4 * 4 + 0] * inv; v.y = p[i4 * 4 + 1] * inv;
            v.z = p[i4 * 4 + 2] * inv; v.w = p[i4 * 4 + 3] * inv;
            *(float4*)(orow + i4 * 64 + cl * 4) = v;
        }
    }
}

// ---- K2: PV. Stage attn rows (f32, contiguous) -> LDS bf16; MFMA with ----
// frag-major sentFB; write X[b][t'][k] bf16 row-major (flat-reshape baked).
__global__ __launch_bounds__(512) void k_pv(const float* __restrict__ attnf,
                                            const unsigned short* __restrict__ sentFB,
                                            const float* __restrict__ atr,
                                            unsigned short* __restrict__ Xws) {
    int tt = blockIdx.x;            // 0..3
    int a  = blockIdx.y;            // 0..7
    int bb = blockIdx.z;            // 0..15
    int tid = threadIdx.x;
    int wv = tid >> 6, lane = tid & 63, quad = lane >> 4, l16 = lane & 15;
    int mg = wv >> 2, eg = wv & 3;
    float av = atr[bb * At + a];

    __shared__ unsigned short Abuf[64 * 512];   // 64 KB, XOR-chunk swizzled

    const float* attn_rows = attnf + ((size_t)(bb * At + a) * Tt + tt * 128) * Tt;
    int rhat = tid >> 3;            // 0..63 staging row
    int hb   = tid & 7;

    for (int pass = 0; pass < 2; ++pass) {
        // stage 64 attn rows (f32 -> bf16), fully coalesced row reads
        const float* src = attn_rows + (size_t)(pass * 64 + rhat) * Tt;
#pragma unroll
        for (int p = 0; p < 8; ++p) {
            int h = hb + 8 * p;                     // chunk of 8 cols
            short8 v = pack8(src + h * 8);
            *(short8*)(Abuf + rhat * 512 + ((h ^ (rhat & 7)) << 3)) = v;
        }
        __syncthreads();

        floatx4 acc[2][4];
#pragma unroll
        for (int mt = 0; mt < 2; ++mt)
#pragma unroll
            for (int i = 0; i < 4; ++i) acc[mt][i] = (floatx4){0.f, 0.f, 0.f, 0.f};

        for (int k0 = 0; k0 < Tt; k0 += 32) {
            short8 bfr[4];
#pragma unroll
            for (int i = 0; i < 4; ++i)
                bfr[i] = *(const short8*)(sentFB +
                    (((size_t)(bb * 16 + eg * 4 + i) * 16 + (k0 >> 5)) << 9) + lane * 8);
#pragma unroll
            for (int mt = 0; mt < 2; ++mt) {
                int mhat = (mg * 2 + mt) * 16 + l16;
                short8 afr = *(const short8*)(Abuf + mhat * 512 +
                    ((((k0 >> 3) + quad) ^ (mhat & 7)) << 3));
#pragma unroll
                for (int i = 0; i < 4; ++i) acc[mt][i] = mfma16(afr, bfr[i], acc[mt][i]);
            }
        }

        // epilogue: X[b][t'][k], t' = a*64 + t>>3, k = (t&7)*256 + e
#pragma unroll
        for (int mt = 0; mt < 2; ++mt)
#pragma unroll
            for (int i = 0; i < 4; ++i) {
                int e = (eg * 4 + i) * 16 + l16;
#pragma unroll
                for (int r = 0; r < 4; ++r) {
                    int tg = tt * 128 + pass * 64 + (mg * 2 + mt) * 16 + quad * 4 + r;
                    int tp = a * 64 + (tg >> 3);
                    int k  = (tg & 7) * 256 + e;
                    Xws[((size_t)bb * Tt + tp) * 2048 + k] = f2bf(av * acc[mt][i][r]);
                }
            }
        __syncthreads();
    }
}

// ---- K3: out = X @ W^T + bias. Stage X rows -> LDS; frag-major Wp. -------
__global__ __launch_bounds__(256) void k_out(const unsigned short* __restrict__ Xws,
                                             const unsigned short* __restrict__ Wp,
                                             const float* __restrict__ bias,
                                             float* __restrict__ out) {
    int bb = blockIdx.y;            // 16
    int tp0 = blockIdx.x * 16;      // 32 tiles
    int tid = threadIdx.x;
    int wv = tid >> 6, lane = tid & 63, quad = lane >> 4, l16 = lane & 15;

    __shared__ unsigned short Xb[16 * 2048];    // 64 KB, XOR-chunk swizzled

    // stage: 16 rows x 4 KB, coalesced
    int rhat = tid >> 4;            // 0..15
    int hb   = tid & 15;
    const unsigned short* src = Xws + ((size_t)bb * Tt + tp0 + rhat) * 2048;
#pragma unroll
    for (int p = 0; p < 16; ++p) {
        int h = hb + 16 * p;                    // 256 chunks/row
        short8 v = *(const short8*)(src + h * 8);
        *(short8*)(Xb + rhat * 2048 + ((h ^ (rhat & 7)) << 3)) = v;
    }
    __syncthreads();

    floatx4 oacc[4];
#pragma unroll
    for (int i = 0; i < 4; ++i) oacc[i] = (floatx4){0.f, 0.f, 0.f, 0.f};

    const int KK = At * Et;  // 2048
    for (int k0 = 0; k0 < KK; k0 += 32) {
        short8 afr = *(const short8*)(Xb + l16 * 2048 +
            ((((k0 >> 3) + quad) ^ (l16 & 7)) << 3));
#pragma unroll
        for (int i = 0; i < 4; ++i) {
            short8 bf = *(const short8*)(Wp +
                (((size_t)(wv * 4 + i) * 64 + (k0 >> 5)) << 9) + lane * 8);
            oacc[i] = mfma16(afr, bf, oacc[i]);
        }
    }
#pragma unroll
    for (int i = 0; i < 4; ++i) {
        int n = (wv * 4 + i) * 16 + l16;
        float bv = bias[n];
#pragma unroll
        for (int r = 0; r < 4; ++r) {
            int tp = tp0 + quad * 4 + r;
            out[((size_t)bb * Tt + tp) * Et + n] = oacc[i][r] + bv;
        }
    }
}

extern "C" void kernel_launch(void* const* d_in, const int* in_sizes, int n_in,
                              void* d_out, int out_size, void* d_ws, size_t ws_size,
                              hipStream_t stream) {
    const float* sent = (const float*)d_in[0];   // f32 (B,T,E)
    const int*   mask = (const int*)d_in[1];     // int32 (B,T)
    const float* atr  = (const float*)d_in[2];   // f32 (B,A)
    const float* W    = (const float*)d_in[3];   // f32 (E, A*E)
    const float* bias = (const float*)d_in[4];   // f32 (E)

    float* out0  = (float*)d_out;                     // 2,097,152 f32
    float* attnf = out0 + (size_t)Bt * Tt * Et;       // 33,554,432 f32

    char* ws = (char*)d_ws;
    unsigned short* sentbf = (unsigned short*)(ws);             // 4 MB row-major bf16
    unsigned short* sentFB = (unsigned short*)(ws + 4194304);   // 4 MB frag-major
    unsigned short* Wp     = (unsigned short*)(ws + 8388608);   // 1 MB frag-major
    unsigned short* Xws    = (unsigned short*)(ws + 9437184);   // 16 MB X row-major
    // total 25.4 MB (<= 43 MB proven safe)

    hipLaunchKernelGGL(k_prep_sent, dim3(Tt / 32, Et / 32, Bt), dim3(256), 0, stream,
                       sent, sentbf, sentFB);
    hipLaunchKernelGGL(k_prep_w, dim3(16), dim3(256), 0, stream, W, Wp);
    hipLaunchKernelGGL(k_attn, dim3(Tt / 16, Bt), dim3(256), 0, stream,
                       sentbf, mask, atr, attnf);
    hipLaunchKernelGGL(k_pv, dim3(4, At, Bt), dim3(512), 0, stream,
                       attnf, sentFB, atr, Xws);
    hipLaunchKernelGGL(k_out, dim3(Tt / 16, Bt), dim3(256), 0, stream,
                       Xws, Wp, bias, out0);
}

// Round 10
// 221.438 us; speedup vs baseline: 1.4207x; 1.4207x over previous
//
#include <hip/hip_runtime.h>
#include <hip/hip_bf16.h>

// B=16, T=512, E=256, A=8. Inputs f32 (+int32 mask), outputs f32:
//   d_out: [ output 16*512*256 | attn 128*512*512 ]
// R10: fused attn+PV. Per (t0,bb) block: Gram via MFMA (frag-major sentG),
// masked S, per-a softmax -> attn f32 (coalesced) -> P via LDS (A-frag
// chunk-XOR layout, verified R9) -> PV MFMA vs sentFB (verified R9) ->
// X rows staged in LDS, stored contiguous (kills R9's 4x write amplification).
// Then k_out (verified R9): X @ W^T + bias with frag-major Wp.

#define Bt 16
#define Tt 512
#define Et 256
#define At 8

typedef __attribute__((ext_vector_type(8))) short short8;   // 8 x bf16
typedef __attribute__((ext_vector_type(4))) float floatx4;

static __device__ __forceinline__ unsigned short f2bf(float x) {
    union { float f; unsigned u; } v; v.f = x;
    unsigned r = v.u + 0x7fffu + ((v.u >> 16) & 1u);  // RNE
    return (unsigned short)(r >> 16);
}

static __device__ __forceinline__ floatx4 mfma16(short8 a, short8 b, floatx4 c) {
    return __builtin_amdgcn_mfma_f32_16x16x32_bf16(a, b, c, 0, 0, 0);
}

// ---- prep: sentG (Gram frags, k=e) + sentFB (PV B-frags, k=s) ------------
// sentG block (bb, st in [0,32), ec in [0,8)): 512 shorts lane-major;
//   elem(l16,quad,j) = sent[bb][st*16+l16][ec*32+quad*8+j]
// sentFB block (bb, et in [0,16), sc in [0,16)):
//   elem(l16,quad,j) = sent[bb][sc*32+quad*8+j][et*16+l16]
__global__ __launch_bounds__(256) void k_prep_sent(const float* __restrict__ sent,
                                                   unsigned short* __restrict__ sentG,
                                                   unsigned short* __restrict__ sentFB) {
    int bb = blockIdx.z;
    int s0 = blockIdx.x * 32;       // 16
    int e0 = blockIdx.y * 32;       // 8
    __shared__ float tile[32][33];
    int c  = threadIdx.x & 31;
    int r4 = threadIdx.x >> 5;
    for (int i = 0; i < 4; ++i) {
        int r = r4 + 8 * i;
        tile[r][c] = sent[(bb * Tt + s0 + r) * Et + e0 + c];
    }
    __syncthreads();
    int wv = threadIdx.x >> 6, lane = threadIdx.x & 63, quad = lane >> 4, l16 = lane & 15;
    union { short8 s; unsigned short e[8]; } u;
    if (wv < 2) {
        // sentG block (bb, st = s0/16 + wv, ec = e0/32)
#pragma unroll
        for (int j = 0; j < 8; ++j) u.e[j] = f2bf(tile[wv * 16 + l16][quad * 8 + j]);
        *(short8*)(sentG + (((size_t)(bb * 32 + (s0 >> 4) + wv)) * 8 + (e0 >> 5)) * 512
                   + lane * 8) = u.s;
    } else {
        int h = wv - 2;
        // sentFB block (bb, et = e0/16 + h, sc = s0/32)
#pragma unroll
        for (int j = 0; j < 8; ++j) u.e[j] = f2bf(tile[quad * 8 + j][h * 16 + l16]);
        *(short8*)(sentFB + (((size_t)(bb * 16 + (e0 >> 4) + h)) * 16 + (s0 >> 5)) * 512
                   + lane * 8) = u.s;
    }
}

// ---- prep: Wp (B-frag-major W), verified R9 ------------------------------
__global__ __launch_bounds__(256) void k_prep_w(const float* __restrict__ W,
                                                unsigned short* __restrict__ Wp) {
    int nt = blockIdx.x;                  // 16
    int wave = threadIdx.x >> 6, lane = threadIdx.x & 63, quad = lane >> 4, l16 = lane & 15;
    const int KK = At * Et;               // 2048
    for (int p = 0; p < 16; ++p) {
        int kc = wave + 4 * p;            // 64
        const float* src = W + (size_t)(nt * 16 + l16) * KK + kc * 32 + quad * 8;
        union { short8 s; unsigned short e[8]; } u;
#pragma unroll
        for (int j = 0; j < 8; ++j) u.e[j] = f2bf(src[j]);
        *(short8*)(Wp + (((size_t)nt * 64 + kc) << 9) + lane * 8) = u.s;
    }
}

// ---- fused: Gram + softmax + attn store + PV + X store -------------------
__global__ __launch_bounds__(256) void k_attnpv(const unsigned short* __restrict__ sentG,
                                                const unsigned short* __restrict__ sentFB,
                                                const int* __restrict__ mask,
                                                const float* __restrict__ atr,
                                                float* __restrict__ attnf,
                                                unsigned short* __restrict__ Xws) {
    int bb = blockIdx.y;            // 16
    int t0 = blockIdx.x * 16;       // 32 tiles
    __shared__ float S[16][516];    // 33 KB; reused as Pb(16KB)+Xb(8KB) in a-loop
    __shared__ float msk[512];
    __shared__ float mrowv[16];
    unsigned short* Pb = (unsigned short*)&S[0][0];   // 16 rows x 512 bf16
    unsigned short* Xb = Pb + 8192;                    // 2 rows x 2048 bf16

    int tid = threadIdx.x;
    for (int i = tid; i < 512; i += 256) msk[i] = (mask[bb * Tt + i] != 0) ? 1.0f : 0.0f;
    if (tid < 16) mrowv[tid] = (mask[bb * Tt + t0 + tid] != 0) ? 1.0f : 0.0f;
    __syncthreads();

    int wv = tid >> 6, lane = tid & 63, quad = lane >> 4, l16 = lane & 15;

    // ---- Gram: A and B frags both from frag-major sentG (contiguous 1KB/wave)
    const unsigned short* Gbase = sentG + ((size_t)(bb * 32 + (t0 >> 4)) * 8) * 512 + lane * 8;
    short8 af[8];
#pragma unroll
    for (int kk = 0; kk < 8; ++kk) af[kk] = *(const short8*)(Gbase + kk * 512);

#pragma unroll
    for (int i = 0; i < 8; ++i) {
        int nt = wv * 8 + i;
        const unsigned short* Bb = sentG + ((size_t)(bb * 32 + nt) * 8) * 512 + lane * 8;
        floatx4 c = {0.f, 0.f, 0.f, 0.f};
#pragma unroll
        for (int kk = 0; kk < 8; ++kk)
            c = mfma16(af[kk], *(const short8*)(Bb + kk * 512), c);
#pragma unroll
        for (int r = 0; r < 4; ++r) {
            int cidx = nt * 16 + l16;
            S[quad * 4 + r][cidx] = c[r] * msk[cidx] * mrowv[quad * 4 + r];
        }
    }
    __syncthreads();

    // ---- hoist masked scores to regs; one max-reduction for all 8 attrs
    int row = tid >> 4, cl = tid & 15;
    float w[32];
    float wmax = -1e30f;
#pragma unroll
    for (int i4 = 0; i4 < 8; ++i4) {
        float4 v = *(const float4*)&S[row][i4 * 64 + cl * 4];
        w[i4 * 4 + 0] = v.x; w[i4 * 4 + 1] = v.y; w[i4 * 4 + 2] = v.z; w[i4 * 4 + 3] = v.w;
        wmax = fmaxf(wmax, fmaxf(fmaxf(v.x, v.y), fmaxf(v.z, v.w)));
    }
#pragma unroll
    for (int off = 8; off >= 1; off >>= 1) wmax = fmaxf(wmax, __shfl_xor(wmax, off, 64));
    __syncthreads();    // all S reads done before Pb overwrites the region

    for (int a = 0; a < At; ++a) {
        float av = atr[bb * At + a];
        float coef = av * av * (1.0f / 16.0f);
        float mx = coef * wmax;
        float p[32];
        float sum = 0.f;
#pragma unroll
        for (int j = 0; j < 32; ++j) {
            float e = __expf(fmaf(coef, w[j], -mx));
            p[j] = e;
            sum += e;
        }
#pragma unroll
        for (int off = 8; off >= 1; off >>= 1) sum += __shfl_xor(sum, off, 64);
        float inv = 1.0f / sum;
#pragma unroll
        for (int j = 0; j < 32; ++j) p[j] *= inv;

        // attn f32 store (coalesced, verified R9)
        float* orow = attnf + ((size_t)(bb * At + a) * Tt + (t0 + row)) * Tt;
#pragma unroll
        for (int i4 = 0; i4 < 8; ++i4) {
            float4 v;
            v.x = p[i4 * 4 + 0]; v.y = p[i4 * 4 + 1];
            v.z = p[i4 * 4 + 2]; v.w = p[i4 * 4 + 3];
            *(float4*)(orow + i4 * 64 + cl * 4) = v;
        }

        // P -> LDS bf16 in chunk-XOR A-frag layout (cols i4*64+cl*4..+3)
#pragma unroll
        for (int i4 = 0; i4 < 8; ++i4) {
            unsigned a0 = __float_as_uint(p[i4 * 4 + 0]) + 0x8000u;
            unsigned a1 = __float_as_uint(p[i4 * 4 + 1]) + 0x8000u;
            unsigned a2 = __float_as_uint(p[i4 * 4 + 2]) + 0x8000u;
            unsigned a3 = __float_as_uint(p[i4 * 4 + 3]) + 0x8000u;
            uint2 pk;
            pk.x = __builtin_amdgcn_perm(a1, a0, 0x07060302u);
            pk.y = __builtin_amdgcn_perm(a3, a2, 0x07060302u);
            int h = i4 * 8 + (cl >> 1);
            *(uint2*)(Pb + row * 512 + ((h ^ (row & 7)) << 3) + (cl & 1) * 4) = pk;
        }
        __syncthreads();

        // PV: 16x256 = P(16x512) @ sf^T; wave wv owns e-tiles wv*4..+3
        floatx4 pacc[4];
#pragma unroll
        for (int i = 0; i < 4; ++i) pacc[i] = (floatx4){0.f, 0.f, 0.f, 0.f};
        for (int kc = 0; kc < 16; ++kc) {
            short8 afr = *(const short8*)(Pb + l16 * 512 +
                (((kc * 4 + quad) ^ (l16 & 7)) << 3));
#pragma unroll
            for (int i = 0; i < 4; ++i) {
                short8 bfr = *(const short8*)(sentFB +
                    (((size_t)(bb * 16 + wv * 4 + i) * 16 + kc) << 9) + lane * 8);
                pacc[i] = mfma16(afr, bfr, pacc[i]);
            }
        }

        // epilogue: X[b][t'][k], t' = a*64 + (t0>>3) + g, k = (tl&7)*256 + e
#pragma unroll
        for (int i = 0; i < 4; ++i) {
            int e = (wv * 4 + i) * 16 + l16;
#pragma unroll
            for (int r = 0; r < 4; ++r) {
                int tl = quad * 4 + r;
                Xb[(tl >> 3) * 2048 + (tl & 7) * 256 + e] = f2bf(av * pacc[i][r]);
            }
        }
        __syncthreads();

        // Xb -> Xws: 2 contiguous 4 KB rows
        {
            size_t xbase = ((size_t)bb * Tt + a * 64 + (t0 >> 3)) * 2048;
            int g = tid >> 7, off = (tid & 127) * 16;
            short8 v0 = *(const short8*)(Xb + g * 2048 + off);
            short8 v1 = *(const short8*)(Xb + g * 2048 + off + 8);
            *(short8*)(Xws + xbase + g * 2048 + off) = v0;
            *(short8*)(Xws + xbase + g * 2048 + off + 8) = v1;
        }
        // no sync needed: next a's Xb writes are ordered after its Pb-sync
    }
}

// ---- K3: out = X @ W^T + bias (verified R9) ------------------------------
__global__ __launch_bounds__(256) void k_out(const unsigned short* __restrict__ Xws,
                                             const unsigned short* __restrict__ Wp,
                                             const float* __restrict__ bias,
                                             float* __restrict__ out) {
    int bb = blockIdx.y;            // 16
    int tp0 = blockIdx.x * 16;      // 32 tiles
    int tid = threadIdx.x;
    int wv = tid >> 6, lane = tid & 63, quad = lane >> 4, l16 = lane & 15;

    __shared__ unsigned short Xb[16 * 2048];    // 64 KB, XOR-chunk swizzled

    int rhat = tid >> 4;            // 0..15
    int hb   = tid & 15;
    const unsigned short* src = Xws + ((size_t)bb * Tt + tp0 + rhat) * 2048;
#pragma unroll
    for (int p = 0; p < 16; ++p) {
        int h = hb + 16 * p;
        short8 v = *(const short8*)(src + h * 8);
        *(short8*)(Xb + rhat * 2048 + ((h ^ (rhat & 7)) << 3)) = v;
    }
    __syncthreads();

    floatx4 oacc[4];
#pragma unroll
    for (int i = 0; i < 4; ++i) oacc[i] = (floatx4){0.f, 0.f, 0.f, 0.f};

    const int KK = At * Et;  // 2048
    for (int k0 = 0; k0 < KK; k0 += 32) {
        short8 afr = *(const short8*)(Xb + l16 * 2048 +
            ((((k0 >> 3) + quad) ^ (l16 & 7)) << 3));
#pragma unroll
        for (int i = 0; i < 4; ++i) {
            short8 bf = *(const short8*)(Wp +
                (((size_t)(wv * 4 + i) * 64 + (k0 >> 5)) << 9) + lane * 8);
            oacc[i] = mfma16(afr, bf, oacc[i]);
        }
    }
#pragma unroll
    for (int i = 0; i < 4; ++i) {
        int n = (wv * 4 + i) * 16 + l16;
        float bv = bias[n];
#pragma unroll
        for (int r = 0; r < 4; ++r) {
            int tp = tp0 + quad * 4 + r;
            out[((size_t)bb * Tt + tp) * Et + n] = oacc[i][r] + bv;
        }
    }
}

extern "C" void kernel_launch(void* const* d_in, const int* in_sizes, int n_in,
                              void* d_out, int out_size, void* d_ws, size_t ws_size,
                              hipStream_t stream) {
    const float* sent = (const float*)d_in[0];   // f32 (B,T,E)
    const int*   mask = (const int*)d_in[1];     // int32 (B,T)
    const float* atr  = (const float*)d_in[2];   // f32 (B,A)
    const float* W    = (const float*)d_in[3];   // f32 (E, A*E)
    const float* bias = (const float*)d_in[4];   // f32 (E)

    float* out0  = (float*)d_out;                     // 2,097,152 f32
    float* attnf = out0 + (size_t)Bt * Tt * Et;       // 33,554,432 f32

    char* ws = (char*)d_ws;
    unsigned short* sentG  = (unsigned short*)(ws);             // 4 MB
    unsigned short* sentFB = (unsigned short*)(ws + 4194304);   // 4 MB
    unsigned short* Wp     = (unsigned short*)(ws + 8388608);   // 1 MB
    unsigned short* Xws    = (unsigned short*)(ws + 9437184);   // 32 MB
    // total 42.99 MB (== R2/R9 proven-safe footprint)

    hipLaunchKernelGGL(k_prep_sent, dim3(Tt / 32, Et / 32, Bt), dim3(256), 0, stream,
                       sent, sentG, sentFB);
    hipLaunchKernelGGL(k_prep_w, dim3(16), dim3(256), 0, stream, W, Wp);
    hipLaunchKernelGGL(k_attnpv, dim3(Tt / 16, Bt), dim3(256), 0, stream,
                       sentG, sentFB, mask, atr, attnf, Xws);
    hipLaunchKernelGGL(k_out, dim3(Tt / 16, Bt), dim3(256), 0, stream,
                       Xws, Wp, bias, out0);
}